// Round 6
// baseline (493.950 us; speedup 1.0000x reference)
//
#include <hip/hip_runtime.h>
#include <stdint.h>

typedef unsigned long long u64;
typedef unsigned int u32;

#define NCLS 80
#define NA   8400
#define NIMG 32
#define TOPK 1500
#define MAXDET 300
#define NW 24              // ceil(1500/64) words per suppression row
#define NBLK 24            // 64-row blocks in the scan
#define ROWPAD (NBLK * 64) // 1536 padded mask rows per image
#define CONF 0.25f
#define IOU_TH 0.45f

#define CHUNK 2048         // per-block sort size
#define NCH   5            // ceil(8400/2048)
#define CAND  1500         // sorted candidates kept per chunk

// ---- workspace layout (bytes) ----
#define OFF_CAND   ((size_t)0)                             // NIMG*NCH*CAND*8
#define OFF_TBOX   (OFF_CAND + (size_t)NIMG*NCH*CAND*8)    // NIMG*TOPK*16
#define OFF_TNMS   (OFF_TBOX + (size_t)NIMG*TOPK*16)       // NIMG*TOPK*16
#define OFF_TSC    (OFF_TNMS + (size_t)NIMG*TOPK*16)       // NIMG*TOPK*4
#define OFF_TCL    (OFF_TSC  + (size_t)NIMG*TOPK*4)        // NIMG*TOPK*4
#define OFF_MASK   (OFF_TCL  + (size_t)NIMG*TOPK*4)        // NIMG*ROWPAD*NW*8
#define WS_NEED    (OFF_MASK + (size_t)NIMG*ROWPAD*NW*8)   // ~13.2 MB

// key = [~ordered(msc):32][anchor:14][cls:7][0:11]
// ascending key == descending score, ties by ascending anchor (lax.top_k exact).

// ---------------------------------------------------------------------------
// Kernel 1: fused score/argmax + chunk bitonic sort (2048/block).
// ---------------------------------------------------------------------------
__global__ __launch_bounds__(1024) void k_sortchunk(const float* __restrict__ pred,
                                                    u64* __restrict__ cand) {
    __shared__ u64 s[CHUNK];
    const int tid = threadIdx.x;
    const int c = blockIdx.x;
    const int b = blockIdx.y;
    const int a0 = c * CHUNK;
    const float* pb = pred + (size_t)b * (4 + NCLS) * NA;

    for (int i = tid; i < CHUNK; i += 1024) {
        int a = a0 + i;
        u64 key = ~0ULL;
        if (a < NA) {
            float best = pb[(size_t)4 * NA + a];
            int bi = 0;
#pragma unroll 8
            for (int cc = 1; cc < NCLS; ++cc) {
                float v = pb[(size_t)(4 + cc) * NA + a];
                if (v > best) { best = v; bi = cc; }   // strict >: first max (jnp.argmax)
            }
            float msc = (best > CONF) ? best : -1.0f;
            u32 u = __float_as_uint(msc);
            u = (u & 0x80000000u) ? ~u : (u | 0x80000000u);
            key = ((u64)(~u) << 32) | ((u64)(u32)a << 18) | ((u64)(u32)bi << 11);
        }
        s[i] = key;
    }
    __syncthreads();

    for (u32 k = 2; k <= CHUNK; k <<= 1) {
        for (u32 j = k >> 1; j > 0; j >>= 1) {
            int t = tid;
            int i = 2 * t - (t & (j - 1));
            u64 x = s[i], y = s[i + j];
            bool asc = (i & k) == 0;
            if ((x > y) == asc) { s[i] = y; s[i + j] = x; }
            __syncthreads();
        }
    }

    u64* cb = cand + ((size_t)b * NCH + c) * CAND;
    for (int i = tid; i < CAND; i += 1024) cb[i] = s[i];
}

// ---------------------------------------------------------------------------
// Kernel 2: merge 5 sorted lists -> exact top-1500, then gather (contract off).
// ---------------------------------------------------------------------------
__global__ __launch_bounds__(1024) void k_merge_gather(const float* __restrict__ pred,
                                                       const u64* __restrict__ cand,
                                                       float4* __restrict__ tbox,
                                                       float4* __restrict__ tnms,
                                                       float* __restrict__ tsc,
                                                       int* __restrict__ tcl) {
#pragma clang fp contract(off)
    __shared__ u64 sA[CHUNK];
    __shared__ u64 sB[CHUNK];
    const int tid = threadIdx.x;
    const int b = blockIdx.x;
    const u64* cb = cand + (size_t)b * NCH * CAND;

    for (int i = tid; i < CHUNK; i += 1024)
        sA[i] = (i < CAND) ? cb[i] : ~0ULL;

    for (int m = 1; m < NCH; ++m) {
        for (int i = tid; i < CHUNK; i += 1024)
            sB[i] = (i < CAND) ? cb[(size_t)m * CAND + i] : ~0ULL;
        __syncthreads();
        for (int i = tid; i < CHUNK; i += 1024) {     // merge-split: keep lo half
            u64 x = sA[i], y = sB[CHUNK - 1 - i];
            sA[i] = (x < y) ? x : y;
        }
        __syncthreads();
        for (u32 j = CHUNK >> 1; j > 0; j >>= 1) {    // bitonic merge ascending
            int t = tid;
            int i = 2 * t - (t & (j - 1));
            u64 x = sA[i], y = sA[i + j];
            if (x > y) { sA[i] = y; sA[i + j] = x; }
            __syncthreads();
        }
    }

    const float* pb = pred + (size_t)b * (4 + NCLS) * NA;
    const float C1 = (float)((1.0 / 80.0) / 640.0);   // mult / IMGSZ
    const float C2 = (float)(1.0 / 80.0);             // mult
    for (int r = tid; r < TOPK; r += 1024) {
        u64 key = sA[r];
        int a = (int)((key >> 18) & 0x3FFFu);
        int cl = (int)((key >> 11) & 0x7Fu);
        u32 ou = ~((u32)(key >> 32));
        u32 fb = (ou & 0x80000000u) ? (ou ^ 0x80000000u) : ~ou;
        float msc = __uint_as_float(fb);
        float x1 = pb[a], y1 = pb[NA + a], x2 = pb[2 * NA + a], y2 = pb[3 * NA + a];
        float off = (float)cl * C2;
        tbox[b * TOPK + r] = make_float4(x1, y1, x2, y2);
        tnms[b * TOPK + r] = make_float4(x1 * C1 + off, y1 * C1 + off,
                                         x2 * C1 + off, y2 * C1 + off);
        tsc[b * TOPK + r] = msc;
        tcl[b * TOPK + r] = cl;
    }
}

// ---------------------------------------------------------------------------
// Kernel 3: suppression bit matrix (j > i), padded row stride ROWPAD.
// ---------------------------------------------------------------------------
__global__ __launch_bounds__(256) void k_mask(const float4* __restrict__ tnms,
                                              u64* __restrict__ mask) {
#pragma clang fp contract(off)
    __shared__ float4 nb[TOPK];                  // 24 KB
    const int b = blockIdx.y;
    const int tid = threadIdx.x;
    for (int i = tid; i < TOPK; i += 256) nb[i] = tnms[b * TOPK + i];
    __syncthreads();

    const int row0 = blockIdx.x * 125;
    for (int item = tid; item < 125 * NW; item += 256) {
        int r = row0 + item / NW;
        int w = item % NW;
        u64 bits = 0ULL;
        if (w * 64 + 63 > r) {
            float4 bi = nb[r];
            float area_i = (bi.z - bi.x) * (bi.w - bi.y);
            int jmax = min(64, TOPK - w * 64);
            for (int l = 0; l < jmax; ++l) {
                int j = w * 64 + l;
                if (j > r) {
                    float4 bj = nb[j];
                    float lx = fmaxf(bi.x, bj.x), ly = fmaxf(bi.y, bj.y);
                    float rx = fminf(bi.z, bj.z), ry = fminf(bi.w, bj.w);
                    float iw = fmaxf(rx - lx, 0.0f), ih = fmaxf(ry - ly, 0.0f);
                    float inter = iw * ih;
                    float area_j = (bj.z - bj.x) * (bj.w - bj.y);
                    float iou = inter / (area_i + area_j - inter + 1e-7f);
                    if (iou > IOU_TH) bits |= (1ULL << l);
                }
            }
        }
        mask[((size_t)b * ROWPAD + r) * NW + w] = bits;
    }
}

// ---------------------------------------------------------------------------
// Kernel 4: block-parallel greedy scan. 24 blocks of 64 rows; decisions for
// block t depend only on supp word t -> ONE shfl per 64 rows, uniform ALU
// decision chain in all lanes, LDS-staged mask blocks (double-buffered,
// register-staged 2 blocks ahead, wave-synchronous).
// ---------------------------------------------------------------------------
__global__ __launch_bounds__(64) void k_scan(const u64* __restrict__ mask,
                                             const float4* __restrict__ tbox,
                                             const float* __restrict__ tsc,
                                             const int* __restrict__ tcl,
                                             float* __restrict__ out) {
    __shared__ u64 sbuf[2][64 * NW];             // 2 x 12 KiB
    const int b = blockIdx.x;
    const int lane = threadIdx.x;
    float* outb = out + (size_t)b * MAXDET * 6;
    for (int i = lane; i < MAXDET * 6; i += 64) outb[i] = 0.0f;
    __syncthreads();   // drain zero-fill stores before detection writes

    // valid bitset: bit j of word `lane` (lanes 0..23), vectorized float4 reads
    u64 validw = 0ULL;
    if (lane < NW) {
        const float4* t4 = (const float4*)(tsc + (size_t)b * TOPK);
#pragma unroll
        for (int q = 0; q < 16; ++q) {
            int i4 = lane * 16 + q;              // float4 index; lane's rows [64l,64l+64)
            if (i4 < TOPK / 4) {
                float4 v = t4[i4];
                int base = q * 4;
                if (v.x > CONF) validw |= (1ULL << (base + 0));
                if (v.y > CONF) validw |= (1ULL << (base + 1));
                if (v.z > CONF) validw |= (1ULL << (base + 2));
                if (v.w > CONF) validw |= (1ULL << (base + 3));
            }
        }
    }
    u64 acc = (lane < NW) ? ~validw : ~0ULL;     // supp word `lane`; pads pre-suppressed

    const u64* mbase = mask + (size_t)b * ROWPAD * NW;
    const uint4* g4 = (const uint4*)mbase;       // 768 uint4 per 64-row block
    uint4* l4_0 = (uint4*)&sbuf[0][0];
    uint4* l4_1 = (uint4*)&sbuf[1][0];
    const int ml = (lane < NW) ? lane : 0;       // clamped word index for apply

    uint4 rA[12], rB[12];
#pragma unroll
    for (int i = 0; i < 12; ++i) rA[i] = g4[0 * 768 + i * 64 + lane];   // blk0
#pragma unroll
    for (int i = 0; i < 12; ++i) rB[i] = g4[1 * 768 + i * 64 + lane];   // blk1
#pragma unroll
    for (int i = 0; i < 12; ++i) l4_0[i * 64 + lane] = rA[i];           // buf0 <- blk0
#pragma unroll
    for (int i = 0; i < 12; ++i) rA[i] = g4[2 * 768 + i * 64 + lane];   // blk2

#pragma unroll
    for (int tt = 0; tt < 12; ++tt) {
        const int t0 = 2 * tt, t1 = 2 * tt + 1;
        // --- even step: write blk t0+1 (odd -> rB -> buf1), issue blk t0+3 -> rB
        {
#pragma unroll
            for (int i = 0; i < 12; ++i) l4_1[i * 64 + lane] = rB[i];
            if (t0 + 3 < NBLK) {
#pragma unroll
                for (int i = 0; i < 12; ++i) rB[i] = g4[(size_t)(t0 + 3) * 768 + i * 64 + lane];
            }
            // process block t0 from sbuf[0]
            const u64* ss = &sbuf[0][0];
            u64 sw = __shfl(acc, t0);
            u64 kb = 0ULL;
#pragma unroll 8
            for (int ii = 0; ii < 64; ++ii) {
                u64 mi = ss[ii * NW + t0];       // uniform broadcast read
                if (!((sw >> ii) & 1ULL)) { sw |= mi; kb |= (1ULL << ii); }
            }
            while (kb) {                          // apply kept rows' ORs to acc
                int ii = __ffsll((long long)kb) - 1;
                kb &= kb - 1;
                acc |= ss[ii * NW + ml];
            }
        }
        // --- odd step: write blk t1+1 (even -> rA -> buf0), issue blk t1+3 -> rA
        {
            if (t1 + 1 < NBLK) {
#pragma unroll
                for (int i = 0; i < 12; ++i) l4_0[i * 64 + lane] = rA[i];
            }
            if (t1 + 3 < NBLK) {
#pragma unroll
                for (int i = 0; i < 12; ++i) rA[i] = g4[(size_t)(t1 + 3) * 768 + i * 64 + lane];
            }
            // process block t1 from sbuf[1]
            const u64* ss = &sbuf[1][0];
            u64 sw = __shfl(acc, t1);
            u64 kb = 0ULL;
#pragma unroll 8
            for (int ii = 0; ii < 64; ++ii) {
                u64 mi = ss[ii * NW + t1];
                if (!((sw >> ii) & 1ULL)) { sw |= mi; kb |= (1ULL << ii); }
            }
            while (kb) {
                int ii = __ffsll((long long)kb) - 1;
                kb &= kb - 1;
                acc |= ss[ii * NW + ml];
            }
        }
    }

    // compaction: keep = ~supp (invalid & pad bits already 1 in acc)
    u64 keepw = (lane < NW) ? ~acc : 0ULL;
    int cnt = __popcll(keepw);
    int pre = cnt;
#pragma unroll
    for (int d = 1; d < 64; d <<= 1) {
        int o = __shfl_up(pre, d);
        if (lane >= d) pre += o;
    }
    int rbase = pre - cnt;
    u64 m = keepw;
    int idx = 0;
    while (m) {
        int l = __ffsll((long long)m) - 1;
        m &= m - 1;
        int r = rbase + idx; ++idx;
        if (r < MAXDET) {
            int j = lane * 64 + l;
            float4 bx = tbox[b * TOPK + j];
            float sc = tsc[b * TOPK + j];
            int c = tcl[b * TOPK + j];
            float* o6 = outb + r * 6;
            o6[0] = bx.x; o6[1] = bx.y; o6[2] = bx.z; o6[3] = bx.w;
            o6[4] = sc;   o6[5] = (float)c;
        }
    }
}

// ---------------------------------------------------------------------------
extern "C" void kernel_launch(void* const* d_in, const int* in_sizes, int n_in,
                              void* d_out, int out_size, void* d_ws, size_t ws_size,
                              hipStream_t stream) {
    const float* pred = (const float*)d_in[0];
    float* out = (float*)d_out;
    char* ws = (char*)d_ws;
    if (ws_size < WS_NEED) return;

    u64*    cand = (u64*)   (ws + OFF_CAND);
    float4* tbox = (float4*)(ws + OFF_TBOX);
    float4* tnms = (float4*)(ws + OFF_TNMS);
    float*  tsc  = (float*) (ws + OFF_TSC);
    int*    tcl  = (int*)   (ws + OFF_TCL);
    u64*    mask = (u64*)   (ws + OFF_MASK);

    k_sortchunk<<<dim3(NCH, NIMG), 1024, 0, stream>>>(pred, cand);
    k_merge_gather<<<NIMG, 1024, 0, stream>>>(pred, cand, tbox, tnms, tsc, tcl);
    k_mask<<<dim3(12, NIMG), 256, 0, stream>>>(tnms, mask);
    k_scan<<<NIMG, 64, 0, stream>>>(mask, tbox, tsc, tcl, out);
}

// Round 7
// 390.993 us; speedup vs baseline: 1.2633x; 1.2633x over previous
//
#include <hip/hip_runtime.h>
#include <stdint.h>

typedef unsigned long long u64;
typedef unsigned int u32;

#define NCLS 80
#define NA   8400
#define NIMG 32
#define TOPK 1500
#define MAXDET 300
#define NW 24              // ceil(1500/64) words per suppression row
#define NBLK 24            // 64-row blocks in the scan
#define ROWPAD (NBLK * 64) // 1536 padded mask rows per image
#define CONF 0.25f
#define IOU_TH 0.45f

#define CHUNK 2048         // per-block sort size
#define NCH   5            // ceil(8400/2048)
#define CAND  1500         // sorted candidates kept per chunk

// ---- workspace layout (bytes) ----
#define OFF_CAND   ((size_t)0)                             // NIMG*NCH*CAND*8
#define OFF_TBOX   (OFF_CAND + (size_t)NIMG*NCH*CAND*8)    // NIMG*TOPK*16
#define OFF_TNMS   (OFF_TBOX + (size_t)NIMG*TOPK*16)       // NIMG*TOPK*16
#define OFF_TSC    (OFF_TNMS + (size_t)NIMG*TOPK*16)       // NIMG*TOPK*4
#define OFF_TCL    (OFF_TSC  + (size_t)NIMG*TOPK*4)        // NIMG*TOPK*4
#define OFF_MASK   (OFF_TCL  + (size_t)NIMG*TOPK*4)        // NIMG*ROWPAD*NW*8
#define WS_NEED    (OFF_MASK + (size_t)NIMG*ROWPAD*NW*8)   // ~13.2 MB

// key = [~ordered(msc):32][anchor:14][cls:7][0:11]
// ascending key == descending score, ties by ascending anchor (lax.top_k exact).

// ---------------------------------------------------------------------------
// Kernel 1: fused score/argmax + chunk bitonic sort (2048/block).
// ---------------------------------------------------------------------------
__global__ __launch_bounds__(1024) void k_sortchunk(const float* __restrict__ pred,
                                                    u64* __restrict__ cand) {
    __shared__ u64 s[CHUNK];
    const int tid = threadIdx.x;
    const int c = blockIdx.x;
    const int b = blockIdx.y;
    const int a0 = c * CHUNK;
    const float* pb = pred + (size_t)b * (4 + NCLS) * NA;

    for (int i = tid; i < CHUNK; i += 1024) {
        int a = a0 + i;
        u64 key = ~0ULL;
        if (a < NA) {
            float best = pb[(size_t)4 * NA + a];
            int bi = 0;
#pragma unroll 8
            for (int cc = 1; cc < NCLS; ++cc) {
                float v = pb[(size_t)(4 + cc) * NA + a];
                if (v > best) { best = v; bi = cc; }   // strict >: first max (jnp.argmax)
            }
            float msc = (best > CONF) ? best : -1.0f;
            u32 u = __float_as_uint(msc);
            u = (u & 0x80000000u) ? ~u : (u | 0x80000000u);
            key = ((u64)(~u) << 32) | ((u64)(u32)a << 18) | ((u64)(u32)bi << 11);
        }
        s[i] = key;
    }
    __syncthreads();

    for (u32 k = 2; k <= CHUNK; k <<= 1) {
        for (u32 j = k >> 1; j > 0; j >>= 1) {
            int t = tid;
            int i = 2 * t - (t & (j - 1));
            u64 x = s[i], y = s[i + j];
            bool asc = (i & k) == 0;
            if ((x > y) == asc) { s[i] = y; s[i + j] = x; }
            __syncthreads();
        }
    }

    u64* cb = cand + ((size_t)b * NCH + c) * CAND;
    for (int i = tid; i < CAND; i += 1024) cb[i] = s[i];
}

// ---------------------------------------------------------------------------
// Kernel 2: merge 5 sorted lists -> exact top-1500, then gather (contract off).
// ---------------------------------------------------------------------------
__global__ __launch_bounds__(1024) void k_merge_gather(const float* __restrict__ pred,
                                                       const u64* __restrict__ cand,
                                                       float4* __restrict__ tbox,
                                                       float4* __restrict__ tnms,
                                                       float* __restrict__ tsc,
                                                       int* __restrict__ tcl) {
#pragma clang fp contract(off)
    __shared__ u64 sA[CHUNK];
    __shared__ u64 sB[CHUNK];
    const int tid = threadIdx.x;
    const int b = blockIdx.x;
    const u64* cb = cand + (size_t)b * NCH * CAND;

    for (int i = tid; i < CHUNK; i += 1024)
        sA[i] = (i < CAND) ? cb[i] : ~0ULL;

    for (int m = 1; m < NCH; ++m) {
        for (int i = tid; i < CHUNK; i += 1024)
            sB[i] = (i < CAND) ? cb[(size_t)m * CAND + i] : ~0ULL;
        __syncthreads();
        for (int i = tid; i < CHUNK; i += 1024) {     // merge-split: keep lo half
            u64 x = sA[i], y = sB[CHUNK - 1 - i];
            sA[i] = (x < y) ? x : y;
        }
        __syncthreads();
        for (u32 j = CHUNK >> 1; j > 0; j >>= 1) {    // bitonic merge ascending
            int t = tid;
            int i = 2 * t - (t & (j - 1));
            u64 x = sA[i], y = sA[i + j];
            if (x > y) { sA[i] = y; sA[i + j] = x; }
            __syncthreads();
        }
    }

    const float* pb = pred + (size_t)b * (4 + NCLS) * NA;
    const float C1 = (float)((1.0 / 80.0) / 640.0);   // mult / IMGSZ
    const float C2 = (float)(1.0 / 80.0);             // mult
    for (int r = tid; r < TOPK; r += 1024) {
        u64 key = sA[r];
        int a = (int)((key >> 18) & 0x3FFFu);
        int cl = (int)((key >> 11) & 0x7Fu);
        u32 ou = ~((u32)(key >> 32));
        u32 fb = (ou & 0x80000000u) ? (ou ^ 0x80000000u) : ~ou;
        float msc = __uint_as_float(fb);
        float x1 = pb[a], y1 = pb[NA + a], x2 = pb[2 * NA + a], y2 = pb[3 * NA + a];
        float off = (float)cl * C2;
        tbox[b * TOPK + r] = make_float4(x1, y1, x2, y2);
        tnms[b * TOPK + r] = make_float4(x1 * C1 + off, y1 * C1 + off,
                                         x2 * C1 + off, y2 * C1 + off);
        tsc[b * TOPK + r] = msc;
        tcl[b * TOPK + r] = cl;
    }
}

// ---------------------------------------------------------------------------
// Kernel 3: suppression bit matrix (j > i), padded row stride ROWPAD.
// ---------------------------------------------------------------------------
__global__ __launch_bounds__(256) void k_mask(const float4* __restrict__ tnms,
                                              u64* __restrict__ mask) {
#pragma clang fp contract(off)
    __shared__ float4 nb[TOPK];                  // 24 KB
    const int b = blockIdx.y;
    const int tid = threadIdx.x;
    for (int i = tid; i < TOPK; i += 256) nb[i] = tnms[b * TOPK + i];
    __syncthreads();

    const int row0 = blockIdx.x * 125;
    for (int item = tid; item < 125 * NW; item += 256) {
        int r = row0 + item / NW;
        int w = item % NW;
        u64 bits = 0ULL;
        if (w * 64 + 63 > r) {
            float4 bi = nb[r];
            float area_i = (bi.z - bi.x) * (bi.w - bi.y);
            int jmax = min(64, TOPK - w * 64);
            for (int l = 0; l < jmax; ++l) {
                int j = w * 64 + l;
                if (j > r) {
                    float4 bj = nb[j];
                    float lx = fmaxf(bi.x, bj.x), ly = fmaxf(bi.y, bj.y);
                    float rx = fminf(bi.z, bj.z), ry = fminf(bi.w, bj.w);
                    float iw = fmaxf(rx - lx, 0.0f), ih = fmaxf(ry - ly, 0.0f);
                    float inter = iw * ih;
                    float area_j = (bj.z - bj.x) * (bj.w - bj.y);
                    float iou = inter / (area_i + area_j - inter + 1e-7f);
                    if (iou > IOU_TH) bits |= (1ULL << l);
                }
            }
        }
        mask[((size_t)b * ROWPAD + r) * NW + w] = bits;
    }
}

// ---------------------------------------------------------------------------
// Kernel 4 v3: block-parallel greedy scan.
//  - closure: lane ii loads row ii's word t with ONE parallel ds_read_b64,
//    readlane(ii) lifts rows to uniform regs -> pure-ALU 64-step chain.
//  - apply: 64 unconditional pipelined ds_read_b64 + cndmask into 4
//    independent OR chains (no read->OR->read serialization).
//  - outer loop rolled (I-cache); rA/rB statically indexed.
// ---------------------------------------------------------------------------
__device__ __forceinline__ void process_block(const u64* ss, int t, u64& acc, int ml) {
    const int lane = threadIdx.x;
    u64 rword = ss[lane * NW + t];           // row `lane`'s word t (one wave-parallel read)
    u64 dead = __shfl(acc, t);               // incoming suppression word t (uniform)
    u64 kb = 0ULL;
#pragma unroll
    for (int ii = 0; ii < 64; ++ii) {        // serial greedy closure, ALU-only
        u32 rlo = (u32)__builtin_amdgcn_readlane((int)(u32)(rword & 0xFFFFFFFFu), ii);
        u32 rhi = (u32)__builtin_amdgcn_readlane((int)(u32)(rword >> 32), ii);
        u64 row = ((u64)rhi << 32) | rlo;
        if (!((dead >> ii) & 1ULL)) { dead |= row; kb |= (1ULL << ii); }
    }
    u64 a0 = 0, a1 = 0, a2 = 0, a3 = 0;      // apply: 4 independent chains
#pragma unroll
    for (int q = 0; q < 16; ++q) {
        u64 v0 = ss[(4 * q + 0) * NW + ml];
        u64 v1 = ss[(4 * q + 1) * NW + ml];
        u64 v2 = ss[(4 * q + 2) * NW + ml];
        u64 v3 = ss[(4 * q + 3) * NW + ml];
        a0 |= ((kb >> (4 * q + 0)) & 1ULL) ? v0 : 0ULL;
        a1 |= ((kb >> (4 * q + 1)) & 1ULL) ? v1 : 0ULL;
        a2 |= ((kb >> (4 * q + 2)) & 1ULL) ? v2 : 0ULL;
        a3 |= ((kb >> (4 * q + 3)) & 1ULL) ? v3 : 0ULL;
    }
    acc |= a0 | a1 | a2 | a3;
}

__global__ __launch_bounds__(64) void k_scan(const u64* __restrict__ mask,
                                             const float4* __restrict__ tbox,
                                             const float* __restrict__ tsc,
                                             const int* __restrict__ tcl,
                                             float* __restrict__ out) {
    __shared__ u64 sbuf[2][64 * NW];             // 2 x 12 KiB
    const int b = blockIdx.x;
    const int lane = threadIdx.x;
    float* outb = out + (size_t)b * MAXDET * 6;
    for (int i = lane; i < MAXDET * 6; i += 64) outb[i] = 0.0f;
    __syncthreads();   // drain zero-fill stores before detection writes

    // valid bitset: bit j of word `lane` (lanes 0..23), vectorized float4 reads
    u64 validw = 0ULL;
    if (lane < NW) {
        const float4* t4 = (const float4*)(tsc + (size_t)b * TOPK);
#pragma unroll
        for (int q = 0; q < 16; ++q) {
            int i4 = lane * 16 + q;
            if (i4 < TOPK / 4) {
                float4 v = t4[i4];
                int base = q * 4;
                if (v.x > CONF) validw |= (1ULL << (base + 0));
                if (v.y > CONF) validw |= (1ULL << (base + 1));
                if (v.z > CONF) validw |= (1ULL << (base + 2));
                if (v.w > CONF) validw |= (1ULL << (base + 3));
            }
        }
    }
    u64 acc = (lane < NW) ? ~validw : ~0ULL;     // supp word `lane`; pads pre-suppressed

    const u64* mbase = mask + (size_t)b * ROWPAD * NW;
    const uint4* g4 = (const uint4*)mbase;       // 768 uint4 per 64-row block
    uint4* l4_0 = (uint4*)&sbuf[0][0];
    uint4* l4_1 = (uint4*)&sbuf[1][0];
    const int ml = (lane < NW) ? lane : 0;       // clamped word index for apply

    uint4 rA[12], rB[12];
#pragma unroll
    for (int i = 0; i < 12; ++i) rA[i] = g4[0 * 768 + i * 64 + lane];   // blk0
#pragma unroll
    for (int i = 0; i < 12; ++i) rB[i] = g4[1 * 768 + i * 64 + lane];   // blk1
#pragma unroll
    for (int i = 0; i < 12; ++i) l4_0[i * 64 + lane] = rA[i];           // buf0 <- blk0
#pragma unroll
    for (int i = 0; i < 12; ++i) rA[i] = g4[2 * 768 + i * 64 + lane];   // blk2

    for (int tt = 0; tt < 12; ++tt) {            // rolled: fits I-cache
        const int t0 = 2 * tt, t1 = 2 * tt + 1;
        // --- even step: write blk t0+1 (rB -> buf1), issue blk t0+3 -> rB
        {
#pragma unroll
            for (int i = 0; i < 12; ++i) l4_1[i * 64 + lane] = rB[i];
            if (t0 + 3 < NBLK) {
#pragma unroll
                for (int i = 0; i < 12; ++i) rB[i] = g4[(size_t)(t0 + 3) * 768 + i * 64 + lane];
            }
            process_block(&sbuf[0][0], t0, acc, ml);
        }
        // --- odd step: write blk t1+1 (rA -> buf0), issue blk t1+3 -> rA
        {
            if (t1 + 1 < NBLK) {
#pragma unroll
                for (int i = 0; i < 12; ++i) l4_0[i * 64 + lane] = rA[i];
            }
            if (t1 + 3 < NBLK) {
#pragma unroll
                for (int i = 0; i < 12; ++i) rA[i] = g4[(size_t)(t1 + 3) * 768 + i * 64 + lane];
            }
            process_block(&sbuf[1][0], t1, acc, ml);
        }
    }

    // compaction: keep = ~supp (invalid & pad bits already 1 in acc)
    u64 keepw = (lane < NW) ? ~acc : 0ULL;
    int cnt = __popcll(keepw);
    int pre = cnt;
#pragma unroll
    for (int d = 1; d < 64; d <<= 1) {
        int o = __shfl_up(pre, d);
        if (lane >= d) pre += o;
    }
    int rbase = pre - cnt;
    u64 m = keepw;
    int idx = 0;
    while (m) {
        int l = __ffsll((long long)m) - 1;
        m &= m - 1;
        int r = rbase + idx; ++idx;
        if (r < MAXDET) {
            int j = lane * 64 + l;
            float4 bx = tbox[b * TOPK + j];
            float sc = tsc[b * TOPK + j];
            int c = tcl[b * TOPK + j];
            float* o6 = outb + r * 6;
            o6[0] = bx.x; o6[1] = bx.y; o6[2] = bx.z; o6[3] = bx.w;
            o6[4] = sc;   o6[5] = (float)c;
        }
    }
}

// ---------------------------------------------------------------------------
extern "C" void kernel_launch(void* const* d_in, const int* in_sizes, int n_in,
                              void* d_out, int out_size, void* d_ws, size_t ws_size,
                              hipStream_t stream) {
    const float* pred = (const float*)d_in[0];
    float* out = (float*)d_out;
    char* ws = (char*)d_ws;
    if (ws_size < WS_NEED) return;

    u64*    cand = (u64*)   (ws + OFF_CAND);
    float4* tbox = (float4*)(ws + OFF_TBOX);
    float4* tnms = (float4*)(ws + OFF_TNMS);
    float*  tsc  = (float*) (ws + OFF_TSC);
    int*    tcl  = (int*)   (ws + OFF_TCL);
    u64*    mask = (u64*)   (ws + OFF_MASK);

    k_sortchunk<<<dim3(NCH, NIMG), 1024, 0, stream>>>(pred, cand);
    k_merge_gather<<<NIMG, 1024, 0, stream>>>(pred, cand, tbox, tnms, tsc, tcl);
    k_mask<<<dim3(12, NIMG), 256, 0, stream>>>(tnms, mask);
    k_scan<<<NIMG, 64, 0, stream>>>(mask, tbox, tsc, tcl, out);
}

// Round 8
// 308.441 us; speedup vs baseline: 1.6014x; 1.2676x over previous
//
#include <hip/hip_runtime.h>
#include <stdint.h>

typedef unsigned long long u64;
typedef unsigned int u32;

#define NCLS 80
#define NA   8400
#define NIMG 32
#define TOPK 1500
#define MAXDET 300
#define NW 24              // ceil(1500/64) words per suppression row
#define NBLK 24            // 64-row blocks in the scan
#define ROWPAD (NBLK * 64) // 1536 padded mask rows per image
#define CONF 0.25f
#define IOU_TH 0.45f

#define CHUNK 2048         // per-block sort size
#define NCH   5            // ceil(8400/2048)
#define CAND  1500         // sorted candidates kept per chunk

// ---- workspace layout (bytes) ----
#define OFF_CAND   ((size_t)0)                             // NIMG*NCH*CAND*8
#define OFF_TBOX   (OFF_CAND + (size_t)NIMG*NCH*CAND*8)    // NIMG*TOPK*16
#define OFF_TNMS   (OFF_TBOX + (size_t)NIMG*TOPK*16)       // NIMG*TOPK*16
#define OFF_TSC    (OFF_TNMS + (size_t)NIMG*TOPK*16)       // NIMG*TOPK*4
#define OFF_TCL    (OFF_TSC  + (size_t)NIMG*TOPK*4)        // NIMG*TOPK*4
#define OFF_MASK   (OFF_TCL  + (size_t)NIMG*TOPK*4)        // NIMG*ROWPAD*NW*8
#define WS_NEED    (OFF_MASK + (size_t)NIMG*ROWPAD*NW*8)   // ~13.2 MB

// key = [~ordered(msc):32][anchor:14][cls:7][0:11]
// ascending key == descending score, ties by ascending anchor (lax.top_k exact).

// ---------------------------------------------------------------------------
// Kernel 1: fused score/argmax + chunk bitonic sort (2048/block).
// ---------------------------------------------------------------------------
__global__ __launch_bounds__(1024) void k_sortchunk(const float* __restrict__ pred,
                                                    u64* __restrict__ cand) {
    __shared__ u64 s[CHUNK];
    const int tid = threadIdx.x;
    const int c = blockIdx.x;
    const int b = blockIdx.y;
    const int a0 = c * CHUNK;
    const float* pb = pred + (size_t)b * (4 + NCLS) * NA;

    for (int i = tid; i < CHUNK; i += 1024) {
        int a = a0 + i;
        u64 key = ~0ULL;
        if (a < NA) {
            float best = pb[(size_t)4 * NA + a];
            int bi = 0;
#pragma unroll 8
            for (int cc = 1; cc < NCLS; ++cc) {
                float v = pb[(size_t)(4 + cc) * NA + a];
                if (v > best) { best = v; bi = cc; }   // strict >: first max (jnp.argmax)
            }
            float msc = (best > CONF) ? best : -1.0f;
            u32 u = __float_as_uint(msc);
            u = (u & 0x80000000u) ? ~u : (u | 0x80000000u);
            key = ((u64)(~u) << 32) | ((u64)(u32)a << 18) | ((u64)(u32)bi << 11);
        }
        s[i] = key;
    }
    __syncthreads();

    for (u32 k = 2; k <= CHUNK; k <<= 1) {
        for (u32 j = k >> 1; j > 0; j >>= 1) {
            int t = tid;
            int i = 2 * t - (t & (j - 1));
            u64 x = s[i], y = s[i + j];
            bool asc = (i & k) == 0;
            if ((x > y) == asc) { s[i] = y; s[i + j] = x; }
            __syncthreads();
        }
    }

    u64* cb = cand + ((size_t)b * NCH + c) * CAND;
    for (int i = tid; i < CAND; i += 1024) cb[i] = s[i];
}

// ---------------------------------------------------------------------------
// Kernel 2: merge 5 sorted lists -> exact top-1500, then gather (contract off).
// ---------------------------------------------------------------------------
__global__ __launch_bounds__(1024) void k_merge_gather(const float* __restrict__ pred,
                                                       const u64* __restrict__ cand,
                                                       float4* __restrict__ tbox,
                                                       float4* __restrict__ tnms,
                                                       float* __restrict__ tsc,
                                                       int* __restrict__ tcl) {
#pragma clang fp contract(off)
    __shared__ u64 sA[CHUNK];
    __shared__ u64 sB[CHUNK];
    const int tid = threadIdx.x;
    const int b = blockIdx.x;
    const u64* cb = cand + (size_t)b * NCH * CAND;

    for (int i = tid; i < CHUNK; i += 1024)
        sA[i] = (i < CAND) ? cb[i] : ~0ULL;

    for (int m = 1; m < NCH; ++m) {
        for (int i = tid; i < CHUNK; i += 1024)
            sB[i] = (i < CAND) ? cb[(size_t)m * CAND + i] : ~0ULL;
        __syncthreads();
        for (int i = tid; i < CHUNK; i += 1024) {     // merge-split: keep lo half
            u64 x = sA[i], y = sB[CHUNK - 1 - i];
            sA[i] = (x < y) ? x : y;
        }
        __syncthreads();
        for (u32 j = CHUNK >> 1; j > 0; j >>= 1) {    // bitonic merge ascending
            int t = tid;
            int i = 2 * t - (t & (j - 1));
            u64 x = sA[i], y = sA[i + j];
            if (x > y) { sA[i] = y; sA[i + j] = x; }
            __syncthreads();
        }
    }

    const float* pb = pred + (size_t)b * (4 + NCLS) * NA;
    const float C1 = (float)((1.0 / 80.0) / 640.0);   // mult / IMGSZ
    const float C2 = (float)(1.0 / 80.0);             // mult
    for (int r = tid; r < TOPK; r += 1024) {
        u64 key = sA[r];
        int a = (int)((key >> 18) & 0x3FFFu);
        int cl = (int)((key >> 11) & 0x7Fu);
        u32 ou = ~((u32)(key >> 32));
        u32 fb = (ou & 0x80000000u) ? (ou ^ 0x80000000u) : ~ou;
        float msc = __uint_as_float(fb);
        float x1 = pb[a], y1 = pb[NA + a], x2 = pb[2 * NA + a], y2 = pb[3 * NA + a];
        float off = (float)cl * C2;
        tbox[b * TOPK + r] = make_float4(x1, y1, x2, y2);
        tnms[b * TOPK + r] = make_float4(x1 * C1 + off, y1 * C1 + off,
                                         x2 * C1 + off, y2 * C1 + off);
        tsc[b * TOPK + r] = msc;
        tcl[b * TOPK + r] = cl;
    }
}

// ---------------------------------------------------------------------------
// Kernel 3 v2: suppression bit matrix, row-per-lane / wave-uniform column.
// grid (NBLK, NIMG) x 256. Lane owns row r = r0 + (tid&63); wave q=tid>>6
// handles words w = q, q+4, ..., q+20. Inner column j is wave-uniform ->
// nb[j] is an LDS broadcast (ZERO bank conflicts). Lower-triangle words
// skipped via uniform branch. nb zero-padded: zero boxes give iou=0.
// ---------------------------------------------------------------------------
__global__ __launch_bounds__(256) void k_mask(const float4* __restrict__ tnms,
                                              u64* __restrict__ mask) {
#pragma clang fp contract(off)
    __shared__ float4 nb[ROWPAD];                // 24 KB, zero-padded to 1536
    const int b = blockIdx.y;
    const int tid = threadIdx.x;
    for (int i = tid; i < ROWPAD; i += 256)
        nb[i] = (i < TOPK) ? tnms[b * TOPK + i]
                           : make_float4(0.0f, 0.0f, 0.0f, 0.0f);
    __syncthreads();

    const int r0 = blockIdx.x * 64;
    const int r = r0 + (tid & 63);
    const int q = tid >> 6;
    const float4 bi = nb[r];
    const float area_i = (bi.z - bi.x) * (bi.w - bi.y);

    u64* mrow = mask + ((size_t)b * ROWPAD + r) * NW;
#pragma unroll
    for (int wi = 0; wi < 6; ++wi) {
        const int w = q + wi * 4;
        u64 bits = 0ULL;
        if (w * 64 + 63 > r0) {                  // uniform: any column j > min row
            const int j0 = w * 64;
#pragma unroll 8
            for (int l = 0; l < 64; ++l) {
                const int j = j0 + l;
                float4 bj = nb[j];               // wave-uniform -> LDS broadcast
                float lx = fmaxf(bi.x, bj.x), ly = fmaxf(bi.y, bj.y);
                float rx = fminf(bi.z, bj.z), ry = fminf(bi.w, bj.w);
                float iw = fmaxf(rx - lx, 0.0f), ih = fmaxf(ry - ly, 0.0f);
                float inter = iw * ih;
                float area_j = (bj.z - bj.x) * (bj.w - bj.y);
                float iou = inter / (area_i + area_j - inter + 1e-7f);
                bits |= ((iou > IOU_TH) && (j > r)) ? (1ULL << l) : 0ULL;
            }
        }
        mrow[w] = bits;
    }
}

// ---------------------------------------------------------------------------
// Kernel 4: block-parallel greedy scan (readlane closure + pipelined apply).
// ---------------------------------------------------------------------------
__device__ __forceinline__ void process_block(const u64* ss, int t, u64& acc, int ml) {
    const int lane = threadIdx.x;
    u64 rword = ss[lane * NW + t];           // row `lane`'s word t (one parallel read)
    u64 dead = __shfl(acc, t);               // incoming suppression word t (uniform)
    u64 kb = 0ULL;
#pragma unroll
    for (int ii = 0; ii < 64; ++ii) {        // serial greedy closure, ALU-only
        u32 rlo = (u32)__builtin_amdgcn_readlane((int)(u32)(rword & 0xFFFFFFFFu), ii);
        u32 rhi = (u32)__builtin_amdgcn_readlane((int)(u32)(rword >> 32), ii);
        u64 row = ((u64)rhi << 32) | rlo;
        if (!((dead >> ii) & 1ULL)) { dead |= row; kb |= (1ULL << ii); }
    }
    u64 a0 = 0, a1 = 0, a2 = 0, a3 = 0;      // apply: 4 independent chains
#pragma unroll
    for (int q = 0; q < 16; ++q) {
        u64 v0 = ss[(4 * q + 0) * NW + ml];
        u64 v1 = ss[(4 * q + 1) * NW + ml];
        u64 v2 = ss[(4 * q + 2) * NW + ml];
        u64 v3 = ss[(4 * q + 3) * NW + ml];
        a0 |= ((kb >> (4 * q + 0)) & 1ULL) ? v0 : 0ULL;
        a1 |= ((kb >> (4 * q + 1)) & 1ULL) ? v1 : 0ULL;
        a2 |= ((kb >> (4 * q + 2)) & 1ULL) ? v2 : 0ULL;
        a3 |= ((kb >> (4 * q + 3)) & 1ULL) ? v3 : 0ULL;
    }
    acc |= a0 | a1 | a2 | a3;
}

__global__ __launch_bounds__(64) void k_scan(const u64* __restrict__ mask,
                                             const float4* __restrict__ tbox,
                                             const float* __restrict__ tsc,
                                             const int* __restrict__ tcl,
                                             float* __restrict__ out) {
    __shared__ u64 sbuf[2][64 * NW];             // 2 x 12 KiB
    const int b = blockIdx.x;
    const int lane = threadIdx.x;
    float* outb = out + (size_t)b * MAXDET * 6;
    for (int i = lane; i < MAXDET * 6; i += 64) outb[i] = 0.0f;
    __syncthreads();   // drain zero-fill stores before detection writes

    // valid bitset: bit j of word `lane` (lanes 0..23), vectorized float4 reads
    u64 validw = 0ULL;
    if (lane < NW) {
        const float4* t4 = (const float4*)(tsc + (size_t)b * TOPK);
#pragma unroll
        for (int q = 0; q < 16; ++q) {
            int i4 = lane * 16 + q;
            if (i4 < TOPK / 4) {
                float4 v = t4[i4];
                int base = q * 4;
                if (v.x > CONF) validw |= (1ULL << (base + 0));
                if (v.y > CONF) validw |= (1ULL << (base + 1));
                if (v.z > CONF) validw |= (1ULL << (base + 2));
                if (v.w > CONF) validw |= (1ULL << (base + 3));
            }
        }
    }
    u64 acc = (lane < NW) ? ~validw : ~0ULL;     // supp word `lane`; pads pre-suppressed

    const u64* mbase = mask + (size_t)b * ROWPAD * NW;
    const uint4* g4 = (const uint4*)mbase;       // 768 uint4 per 64-row block
    uint4* l4_0 = (uint4*)&sbuf[0][0];
    uint4* l4_1 = (uint4*)&sbuf[1][0];
    const int ml = (lane < NW) ? lane : 0;       // clamped word index for apply

    uint4 rA[12], rB[12];
#pragma unroll
    for (int i = 0; i < 12; ++i) rA[i] = g4[0 * 768 + i * 64 + lane];   // blk0
#pragma unroll
    for (int i = 0; i < 12; ++i) rB[i] = g4[1 * 768 + i * 64 + lane];   // blk1
#pragma unroll
    for (int i = 0; i < 12; ++i) l4_0[i * 64 + lane] = rA[i];           // buf0 <- blk0
#pragma unroll
    for (int i = 0; i < 12; ++i) rA[i] = g4[2 * 768 + i * 64 + lane];   // blk2

    for (int tt = 0; tt < 12; ++tt) {            // rolled: fits I-cache
        const int t0 = 2 * tt, t1 = 2 * tt + 1;
        // --- even step: write blk t0+1 (rB -> buf1), issue blk t0+3 -> rB
        {
#pragma unroll
            for (int i = 0; i < 12; ++i) l4_1[i * 64 + lane] = rB[i];
            if (t0 + 3 < NBLK) {
#pragma unroll
                for (int i = 0; i < 12; ++i) rB[i] = g4[(size_t)(t0 + 3) * 768 + i * 64 + lane];
            }
            process_block(&sbuf[0][0], t0, acc, ml);
        }
        // --- odd step: write blk t1+1 (rA -> buf0), issue blk t1+3 -> rA
        {
            if (t1 + 1 < NBLK) {
#pragma unroll
                for (int i = 0; i < 12; ++i) l4_0[i * 64 + lane] = rA[i];
            }
            if (t1 + 3 < NBLK) {
#pragma unroll
                for (int i = 0; i < 12; ++i) rA[i] = g4[(size_t)(t1 + 3) * 768 + i * 64 + lane];
            }
            process_block(&sbuf[1][0], t1, acc, ml);
        }
    }

    // compaction: keep = ~supp (invalid & pad bits already 1 in acc)
    u64 keepw = (lane < NW) ? ~acc : 0ULL;
    int cnt = __popcll(keepw);
    int pre = cnt;
#pragma unroll
    for (int d = 1; d < 64; d <<= 1) {
        int o = __shfl_up(pre, d);
        if (lane >= d) pre += o;
    }
    int rbase = pre - cnt;
    u64 m = keepw;
    int idx = 0;
    while (m) {
        int l = __ffsll((long long)m) - 1;
        m &= m - 1;
        int r = rbase + idx; ++idx;
        if (r < MAXDET) {
            int j = lane * 64 + l;
            float4 bx = tbox[b * TOPK + j];
            float sc = tsc[b * TOPK + j];
            int c = tcl[b * TOPK + j];
            float* o6 = outb + r * 6;
            o6[0] = bx.x; o6[1] = bx.y; o6[2] = bx.z; o6[3] = bx.w;
            o6[4] = sc;   o6[5] = (float)c;
        }
    }
}

// ---------------------------------------------------------------------------
extern "C" void kernel_launch(void* const* d_in, const int* in_sizes, int n_in,
                              void* d_out, int out_size, void* d_ws, size_t ws_size,
                              hipStream_t stream) {
    const float* pred = (const float*)d_in[0];
    float* out = (float*)d_out;
    char* ws = (char*)d_ws;
    if (ws_size < WS_NEED) return;

    u64*    cand = (u64*)   (ws + OFF_CAND);
    float4* tbox = (float4*)(ws + OFF_TBOX);
    float4* tnms = (float4*)(ws + OFF_TNMS);
    float*  tsc  = (float*) (ws + OFF_TSC);
    int*    tcl  = (int*)   (ws + OFF_TCL);
    u64*    mask = (u64*)   (ws + OFF_MASK);

    k_sortchunk<<<dim3(NCH, NIMG), 1024, 0, stream>>>(pred, cand);
    k_merge_gather<<<NIMG, 1024, 0, stream>>>(pred, cand, tbox, tnms, tsc, tcl);
    k_mask<<<dim3(NBLK, NIMG), 256, 0, stream>>>(tnms, mask);
    k_scan<<<NIMG, 64, 0, stream>>>(mask, tbox, tsc, tcl, out);
}

// Round 9
// 255.237 us; speedup vs baseline: 1.9353x; 1.2084x over previous
//
#include <hip/hip_runtime.h>
#include <stdint.h>

typedef unsigned long long u64;
typedef unsigned int u32;

#define NCLS 80
#define NA   8400
#define NIMG 32
#define TOPK 1500
#define MAXDET 300
#define NW 24              // ceil(1500/64) words per suppression row
#define NBLK 24            // 64-row blocks in the scan
#define ROWPAD (NBLK * 64) // 1536 padded mask rows per image
#define CONF 0.25f
#define IOU_TH 0.45f

#define CHUNK 2048         // per-block sort size
#define NCH   5            // ceil(8400/2048)
#define CAND  1500         // sorted candidates kept per chunk

// ---- workspace layout (bytes) ----
#define OFF_CAND   ((size_t)0)                             // NIMG*NCH*CAND*8
#define OFF_TBOX   (OFF_CAND + (size_t)NIMG*NCH*CAND*8)    // NIMG*TOPK*16
#define OFF_TNMS   (OFF_TBOX + (size_t)NIMG*TOPK*16)       // NIMG*TOPK*16
#define OFF_TSC    (OFF_TNMS + (size_t)NIMG*TOPK*16)       // NIMG*TOPK*4
#define OFF_TCL    (OFF_TSC  + (size_t)NIMG*TOPK*4)        // NIMG*TOPK*4
#define OFF_MASK   (OFF_TCL  + (size_t)NIMG*TOPK*4)        // NIMG*ROWPAD*NW*8
#define WS_NEED    (OFF_MASK + (size_t)NIMG*ROWPAD*NW*8)   // ~13.2 MB

// key = [~ordered(msc):32][anchor:14][cls:7][0:11]
// ascending key == descending score, ties by ascending anchor (lax.top_k exact).

// ---------------------------------------------------------------------------
// Kernel 1: fused score/argmax + chunk bitonic sort (2048/block).
// ---------------------------------------------------------------------------
__global__ __launch_bounds__(1024) void k_sortchunk(const float* __restrict__ pred,
                                                    u64* __restrict__ cand) {
    __shared__ u64 s[CHUNK];
    const int tid = threadIdx.x;
    const int c = blockIdx.x;
    const int b = blockIdx.y;
    const int a0 = c * CHUNK;
    const float* pb = pred + (size_t)b * (4 + NCLS) * NA;

    for (int i = tid; i < CHUNK; i += 1024) {
        int a = a0 + i;
        u64 key = ~0ULL;
        if (a < NA) {
            float best = pb[(size_t)4 * NA + a];
            int bi = 0;
#pragma unroll 8
            for (int cc = 1; cc < NCLS; ++cc) {
                float v = pb[(size_t)(4 + cc) * NA + a];
                if (v > best) { best = v; bi = cc; }   // strict >: first max (jnp.argmax)
            }
            float msc = (best > CONF) ? best : -1.0f;
            u32 u = __float_as_uint(msc);
            u = (u & 0x80000000u) ? ~u : (u | 0x80000000u);
            key = ((u64)(~u) << 32) | ((u64)(u32)a << 18) | ((u64)(u32)bi << 11);
        }
        s[i] = key;
    }
    __syncthreads();

    for (u32 k = 2; k <= CHUNK; k <<= 1) {
        for (u32 j = k >> 1; j > 0; j >>= 1) {
            int t = tid;
            int i = 2 * t - (t & (j - 1));
            u64 x = s[i], y = s[i + j];
            bool asc = (i & k) == 0;
            if ((x > y) == asc) { s[i] = y; s[i + j] = x; }
            __syncthreads();
        }
    }

    u64* cb = cand + ((size_t)b * NCH + c) * CAND;
    for (int i = tid; i < CAND; i += 1024) cb[i] = s[i];
}

// ---------------------------------------------------------------------------
// Kernel 2: merge 5 sorted lists -> exact top-1500, then gather (contract off).
// ---------------------------------------------------------------------------
__global__ __launch_bounds__(1024) void k_merge_gather(const float* __restrict__ pred,
                                                       const u64* __restrict__ cand,
                                                       float4* __restrict__ tbox,
                                                       float4* __restrict__ tnms,
                                                       float* __restrict__ tsc,
                                                       int* __restrict__ tcl) {
#pragma clang fp contract(off)
    __shared__ u64 sA[CHUNK];
    __shared__ u64 sB[CHUNK];
    const int tid = threadIdx.x;
    const int b = blockIdx.x;
    const u64* cb = cand + (size_t)b * NCH * CAND;

    for (int i = tid; i < CHUNK; i += 1024)
        sA[i] = (i < CAND) ? cb[i] : ~0ULL;

    for (int m = 1; m < NCH; ++m) {
        for (int i = tid; i < CHUNK; i += 1024)
            sB[i] = (i < CAND) ? cb[(size_t)m * CAND + i] : ~0ULL;
        __syncthreads();
        for (int i = tid; i < CHUNK; i += 1024) {     // merge-split: keep lo half
            u64 x = sA[i], y = sB[CHUNK - 1 - i];
            sA[i] = (x < y) ? x : y;
        }
        __syncthreads();
        for (u32 j = CHUNK >> 1; j > 0; j >>= 1) {    // bitonic merge ascending
            int t = tid;
            int i = 2 * t - (t & (j - 1));
            u64 x = sA[i], y = sA[i + j];
            if (x > y) { sA[i] = y; sA[i + j] = x; }
            __syncthreads();
        }
    }

    const float* pb = pred + (size_t)b * (4 + NCLS) * NA;
    const float C1 = (float)((1.0 / 80.0) / 640.0);   // mult / IMGSZ
    const float C2 = (float)(1.0 / 80.0);             // mult
    for (int r = tid; r < TOPK; r += 1024) {
        u64 key = sA[r];
        int a = (int)((key >> 18) & 0x3FFFu);
        int cl = (int)((key >> 11) & 0x7Fu);
        u32 ou = ~((u32)(key >> 32));
        u32 fb = (ou & 0x80000000u) ? (ou ^ 0x80000000u) : ~ou;
        float msc = __uint_as_float(fb);
        float x1 = pb[a], y1 = pb[NA + a], x2 = pb[2 * NA + a], y2 = pb[3 * NA + a];
        float off = (float)cl * C2;
        tbox[b * TOPK + r] = make_float4(x1, y1, x2, y2);
        tnms[b * TOPK + r] = make_float4(x1 * C1 + off, y1 * C1 + off,
                                         x2 * C1 + off, y2 * C1 + off);
        tsc[b * TOPK + r] = msc;
        tcl[b * TOPK + r] = cl;
    }
}

// ---------------------------------------------------------------------------
// Kernel 3 v2: suppression bit matrix, row-per-lane / wave-uniform column.
// Inner column j is wave-uniform -> nb[j] is an LDS broadcast (no conflicts).
// ---------------------------------------------------------------------------
__global__ __launch_bounds__(256) void k_mask(const float4* __restrict__ tnms,
                                              u64* __restrict__ mask) {
#pragma clang fp contract(off)
    __shared__ float4 nb[ROWPAD];                // 24 KB, zero-padded to 1536
    const int b = blockIdx.y;
    const int tid = threadIdx.x;
    for (int i = tid; i < ROWPAD; i += 256)
        nb[i] = (i < TOPK) ? tnms[b * TOPK + i]
                           : make_float4(0.0f, 0.0f, 0.0f, 0.0f);
    __syncthreads();

    const int r0 = blockIdx.x * 64;
    const int r = r0 + (tid & 63);
    const int q = tid >> 6;
    const float4 bi = nb[r];
    const float area_i = (bi.z - bi.x) * (bi.w - bi.y);

    u64* mrow = mask + ((size_t)b * ROWPAD + r) * NW;
#pragma unroll
    for (int wi = 0; wi < 6; ++wi) {
        const int w = q + wi * 4;
        u64 bits = 0ULL;
        if (w * 64 + 63 > r0) {                  // uniform: any column j > min row
            const int j0 = w * 64;
#pragma unroll 8
            for (int l = 0; l < 64; ++l) {
                const int j = j0 + l;
                float4 bj = nb[j];               // wave-uniform -> LDS broadcast
                float lx = fmaxf(bi.x, bj.x), ly = fmaxf(bi.y, bj.y);
                float rx = fminf(bi.z, bj.z), ry = fminf(bi.w, bj.w);
                float iw = fmaxf(rx - lx, 0.0f), ih = fmaxf(ry - ly, 0.0f);
                float inter = iw * ih;
                float area_j = (bj.z - bj.x) * (bj.w - bj.y);
                float iou = inter / (area_i + area_j - inter + 1e-7f);
                bits |= ((iou > IOU_TH) && (j > r)) ? (1ULL << l) : 0ULL;
            }
        }
        mrow[w] = bits;
    }
}

// ---------------------------------------------------------------------------
// Kernel 4 v4: block-parallel greedy scan with ZERO-BLOCK FAST PATH.
// The suppression mask is typically near-empty (small boxes, same-class-only
// IoU): a 64-row block whose 12KB tile is all zero provably changes nothing
// (no row ORs anything; keep bits = ~acc read at the end). Ballot-gate each
// block: zero -> skip staging/closure/apply; nonzero -> dense LDS path
// (readlane closure + pipelined apply). Worst case == old dense cost.
// ---------------------------------------------------------------------------
__device__ __forceinline__ void dense_block(const u64* ss, int t, u64& acc, int ml) {
    const int lane = threadIdx.x;
    u64 rword = ss[lane * NW + t];           // row `lane`'s word t (one parallel read)
    u64 dead = __shfl(acc, t);               // incoming suppression word t (uniform)
    u64 kb = 0ULL;
#pragma unroll
    for (int ii = 0; ii < 64; ++ii) {        // serial greedy closure, ALU-only
        u32 rlo = (u32)__builtin_amdgcn_readlane((int)(u32)(rword & 0xFFFFFFFFu), ii);
        u32 rhi = (u32)__builtin_amdgcn_readlane((int)(u32)(rword >> 32), ii);
        u64 row = ((u64)rhi << 32) | rlo;
        if (!((dead >> ii) & 1ULL)) { dead |= row; kb |= (1ULL << ii); }
    }
    u64 a0 = 0, a1 = 0, a2 = 0, a3 = 0;      // apply: 4 independent chains
#pragma unroll
    for (int q = 0; q < 16; ++q) {
        u64 v0 = ss[(4 * q + 0) * NW + ml];
        u64 v1 = ss[(4 * q + 1) * NW + ml];
        u64 v2 = ss[(4 * q + 2) * NW + ml];
        u64 v3 = ss[(4 * q + 3) * NW + ml];
        a0 |= ((kb >> (4 * q + 0)) & 1ULL) ? v0 : 0ULL;
        a1 |= ((kb >> (4 * q + 1)) & 1ULL) ? v1 : 0ULL;
        a2 |= ((kb >> (4 * q + 2)) & 1ULL) ? v2 : 0ULL;
        a3 |= ((kb >> (4 * q + 3)) & 1ULL) ? v3 : 0ULL;
    }
    acc |= a0 | a1 | a2 | a3;
}

__device__ __forceinline__ void step_block(uint4 (&R)[12], int t, u64& acc, int ml,
                                           const uint4* g4, u64* sbuf) {
    const int lane = threadIdx.x;
    u32 nz = 0;
#pragma unroll
    for (int i = 0; i < 12; ++i) nz |= (R[i].x | R[i].y | R[i].z | R[i].w);
    const u64 anym = __ballot(nz != 0);      // wave-uniform
    if (anym) {                              // rare: stage to LDS for dense path
        uint4* l4 = (uint4*)sbuf;
#pragma unroll
        for (int i = 0; i < 12; ++i) l4[i * 64 + lane] = R[i];
    }
    if (t + 2 < NBLK) {                      // prefetch block t+2 into R
#pragma unroll
        for (int i = 0; i < 12; ++i) R[i] = g4[(size_t)(t + 2) * 768 + i * 64 + lane];
    }
    if (anym) dense_block(sbuf, t, acc, ml);
    // else: all-zero block -> acc unchanged, nothing else to do
}

__global__ __launch_bounds__(64) void k_scan(const u64* __restrict__ mask,
                                             const float4* __restrict__ tbox,
                                             const float* __restrict__ tsc,
                                             const int* __restrict__ tcl,
                                             float* __restrict__ out) {
    __shared__ u64 sbuf[64 * NW];                // 12 KiB, single buffer
    const int b = blockIdx.x;
    const int lane = threadIdx.x;
    float* outb = out + (size_t)b * MAXDET * 6;
    for (int i = lane; i < MAXDET * 6; i += 64) outb[i] = 0.0f;
    __syncthreads();   // drain zero-fill stores before detection writes

    // valid bitset: bit j of word `lane` (lanes 0..23), vectorized float4 reads
    u64 validw = 0ULL;
    if (lane < NW) {
        const float4* t4 = (const float4*)(tsc + (size_t)b * TOPK);
#pragma unroll
        for (int q = 0; q < 16; ++q) {
            int i4 = lane * 16 + q;
            if (i4 < TOPK / 4) {
                float4 v = t4[i4];
                int base = q * 4;
                if (v.x > CONF) validw |= (1ULL << (base + 0));
                if (v.y > CONF) validw |= (1ULL << (base + 1));
                if (v.z > CONF) validw |= (1ULL << (base + 2));
                if (v.w > CONF) validw |= (1ULL << (base + 3));
            }
        }
    }
    u64 acc = (lane < NW) ? ~validw : ~0ULL;     // supp word `lane`; pads pre-suppressed

    const u64* mbase = mask + (size_t)b * ROWPAD * NW;
    const uint4* g4 = (const uint4*)mbase;       // 768 uint4 per 64-row block
    const int ml = (lane < NW) ? lane : 0;       // clamped word index for apply

    uint4 rA[12], rB[12];
#pragma unroll
    for (int i = 0; i < 12; ++i) rA[i] = g4[0 * 768 + i * 64 + lane];   // blk0
#pragma unroll
    for (int i = 0; i < 12; ++i) rB[i] = g4[1 * 768 + i * 64 + lane];   // blk1

    for (int tt = 0; tt < 12; ++tt) {            // rolled outer loop (I-cache)
        step_block(rA, 2 * tt,     acc, ml, g4, sbuf);   // even block (rA)
        step_block(rB, 2 * tt + 1, acc, ml, g4, sbuf);   // odd block (rB)
    }

    // compaction: keep = ~supp (invalid & pad bits already 1 in acc)
    u64 keepw = (lane < NW) ? ~acc : 0ULL;
    int cnt = __popcll(keepw);
    int pre = cnt;
#pragma unroll
    for (int d = 1; d < 64; d <<= 1) {
        int o = __shfl_up(pre, d);
        if (lane >= d) pre += o;
    }
    int rbase = pre - cnt;
    u64 m = keepw;
    int idx = 0;
    while (m) {
        int l = __ffsll((long long)m) - 1;
        m &= m - 1;
        int r = rbase + idx; ++idx;
        if (r < MAXDET) {
            int j = lane * 64 + l;
            float4 bx = tbox[b * TOPK + j];
            float sc = tsc[b * TOPK + j];
            int c = tcl[b * TOPK + j];
            float* o6 = outb + r * 6;
            o6[0] = bx.x; o6[1] = bx.y; o6[2] = bx.z; o6[3] = bx.w;
            o6[4] = sc;   o6[5] = (float)c;
        }
    }
}

// ---------------------------------------------------------------------------
extern "C" void kernel_launch(void* const* d_in, const int* in_sizes, int n_in,
                              void* d_out, int out_size, void* d_ws, size_t ws_size,
                              hipStream_t stream) {
    const float* pred = (const float*)d_in[0];
    float* out = (float*)d_out;
    char* ws = (char*)d_ws;
    if (ws_size < WS_NEED) return;

    u64*    cand = (u64*)   (ws + OFF_CAND);
    float4* tbox = (float4*)(ws + OFF_TBOX);
    float4* tnms = (float4*)(ws + OFF_TNMS);
    float*  tsc  = (float*) (ws + OFF_TSC);
    int*    tcl  = (int*)   (ws + OFF_TCL);
    u64*    mask = (u64*)   (ws + OFF_MASK);

    k_sortchunk<<<dim3(NCH, NIMG), 1024, 0, stream>>>(pred, cand);
    k_merge_gather<<<NIMG, 1024, 0, stream>>>(pred, cand, tbox, tnms, tsc, tcl);
    k_mask<<<dim3(NBLK, NIMG), 256, 0, stream>>>(tnms, mask);
    k_scan<<<NIMG, 64, 0, stream>>>(mask, tbox, tsc, tcl, out);
}

// Round 10
// 236.436 us; speedup vs baseline: 2.0891x; 1.0795x over previous
//
#include <hip/hip_runtime.h>
#include <stdint.h>

typedef unsigned long long u64;
typedef unsigned int u32;

#define NCLS 80
#define NA   8400
#define NIMG 32
#define TOPK 1500
#define MAXDET 300
#define NW 24              // ceil(1500/64) words per suppression row
#define NBLK 24            // 64-row blocks in the scan
#define ROWPAD (NBLK * 64) // 1536 padded mask rows per image
#define CONF 0.25f
#define IOU_TH 0.45f

#define CHUNK 2048         // per-block sort size
#define NCH   5            // ceil(8400/2048)
#define CAND  1500         // sorted candidates kept per chunk

// ---- workspace layout (bytes) ----
#define OFF_CAND   ((size_t)0)                             // NIMG*NCH*CAND*8
#define OFF_TBOX   (OFF_CAND + (size_t)NIMG*NCH*CAND*8)    // NIMG*TOPK*16
#define OFF_TNMS   (OFF_TBOX + (size_t)NIMG*TOPK*16)       // NIMG*TOPK*16
#define OFF_TSC    (OFF_TNMS + (size_t)NIMG*TOPK*16)       // NIMG*TOPK*4
#define OFF_TCL    (OFF_TSC  + (size_t)NIMG*TOPK*4)        // NIMG*TOPK*4
#define OFF_MASK   (OFF_TCL  + (size_t)NIMG*TOPK*4)        // NIMG*ROWPAD*NW*8
#define WS_NEED    (OFF_MASK + (size_t)NIMG*ROWPAD*NW*8)   // ~13.2 MB

// key = [~ordered(msc):32][anchor:14][cls:7][0:11]
// ascending key == descending score, ties by ascending anchor (lax.top_k exact).

// ---------------------------------------------------------------------------
// Kernel 1: fused score/argmax + chunk bitonic sort (2048/block).
// ---------------------------------------------------------------------------
__global__ __launch_bounds__(1024) void k_sortchunk(const float* __restrict__ pred,
                                                    u64* __restrict__ cand) {
    __shared__ u64 s[CHUNK];
    const int tid = threadIdx.x;
    const int c = blockIdx.x;
    const int b = blockIdx.y;
    const int a0 = c * CHUNK;
    const float* pb = pred + (size_t)b * (4 + NCLS) * NA;

    for (int i = tid; i < CHUNK; i += 1024) {
        int a = a0 + i;
        u64 key = ~0ULL;
        if (a < NA) {
            float best = pb[(size_t)4 * NA + a];
            int bi = 0;
#pragma unroll 8
            for (int cc = 1; cc < NCLS; ++cc) {
                float v = pb[(size_t)(4 + cc) * NA + a];
                if (v > best) { best = v; bi = cc; }   // strict >: first max (jnp.argmax)
            }
            float msc = (best > CONF) ? best : -1.0f;
            u32 u = __float_as_uint(msc);
            u = (u & 0x80000000u) ? ~u : (u | 0x80000000u);
            key = ((u64)(~u) << 32) | ((u64)(u32)a << 18) | ((u64)(u32)bi << 11);
        }
        s[i] = key;
    }
    __syncthreads();

    for (u32 k = 2; k <= CHUNK; k <<= 1) {
        for (u32 j = k >> 1; j > 0; j >>= 1) {
            int t = tid;
            int i = 2 * t - (t & (j - 1));
            u64 x = s[i], y = s[i + j];
            bool asc = (i & k) == 0;
            if ((x > y) == asc) { s[i] = y; s[i + j] = x; }
            __syncthreads();
        }
    }

    u64* cb = cand + ((size_t)b * NCH + c) * CAND;
    for (int i = tid; i < CAND; i += 1024) cb[i] = s[i];
}

// ---------------------------------------------------------------------------
// Kernel 2: merge 5 sorted lists -> exact top-1500, then gather (contract off).
// ---------------------------------------------------------------------------
__global__ __launch_bounds__(1024) void k_merge_gather(const float* __restrict__ pred,
                                                       const u64* __restrict__ cand,
                                                       float4* __restrict__ tbox,
                                                       float4* __restrict__ tnms,
                                                       float* __restrict__ tsc,
                                                       int* __restrict__ tcl) {
#pragma clang fp contract(off)
    __shared__ u64 sA[CHUNK];
    __shared__ u64 sB[CHUNK];
    const int tid = threadIdx.x;
    const int b = blockIdx.x;
    const u64* cb = cand + (size_t)b * NCH * CAND;

    for (int i = tid; i < CHUNK; i += 1024)
        sA[i] = (i < CAND) ? cb[i] : ~0ULL;

    for (int m = 1; m < NCH; ++m) {
        for (int i = tid; i < CHUNK; i += 1024)
            sB[i] = (i < CAND) ? cb[(size_t)m * CAND + i] : ~0ULL;
        __syncthreads();
        for (int i = tid; i < CHUNK; i += 1024) {     // merge-split: keep lo half
            u64 x = sA[i], y = sB[CHUNK - 1 - i];
            sA[i] = (x < y) ? x : y;
        }
        __syncthreads();
        for (u32 j = CHUNK >> 1; j > 0; j >>= 1) {    // bitonic merge ascending
            int t = tid;
            int i = 2 * t - (t & (j - 1));
            u64 x = sA[i], y = sA[i + j];
            if (x > y) { sA[i] = y; sA[i + j] = x; }
            __syncthreads();
        }
    }

    const float* pb = pred + (size_t)b * (4 + NCLS) * NA;
    const float C1 = (float)((1.0 / 80.0) / 640.0);   // mult / IMGSZ
    const float C2 = (float)(1.0 / 80.0);             // mult
    for (int r = tid; r < TOPK; r += 1024) {
        u64 key = sA[r];
        int a = (int)((key >> 18) & 0x3FFFu);
        int cl = (int)((key >> 11) & 0x7Fu);
        u32 ou = ~((u32)(key >> 32));
        u32 fb = (ou & 0x80000000u) ? (ou ^ 0x80000000u) : ~ou;
        float msc = __uint_as_float(fb);
        float x1 = pb[a], y1 = pb[NA + a], x2 = pb[2 * NA + a], y2 = pb[3 * NA + a];
        float off = (float)cl * C2;
        tbox[b * TOPK + r] = make_float4(x1, y1, x2, y2);
        tnms[b * TOPK + r] = make_float4(x1 * C1 + off, y1 * C1 + off,
                                         x2 * C1 + off, y2 * C1 + off);
        tsc[b * TOPK + r] = msc;
        tcl[b * TOPK + r] = cl;
    }
}

// ---------------------------------------------------------------------------
// Kernel 3 v3: suppression bit matrix, column-split + ballot-gated divide.
// grid (36, NIMG): idx<24 -> z=1 (cols 768..1535, all row-blocks);
// idx>=24 -> z=0 (cols 0..767, row-blocks 0..11 only — rb>=12 is entirely
// sub-diagonal there; its zero words are written by the z=1 block).
// Lane owns row, wave-uniform column j -> LDS broadcast, zero conflicts.
// Divide executed only when __ballot(inter>0) — exact (inter==0 => iou=0).
// ---------------------------------------------------------------------------
__global__ __launch_bounds__(256) void k_mask(const float4* __restrict__ tnms,
                                              u64* __restrict__ mask) {
#pragma clang fp contract(off)
    __shared__ float4 nb[768];                   // 12 KB column slice
    const int b = blockIdx.y;
    const int idx = blockIdx.x;
    const int z = (idx < 24) ? 1 : 0;
    const int rb = (idx < 24) ? idx : (idx - 24);
    const int c0 = z * 768;
    const int tid = threadIdx.x;

    for (int i = tid; i < 768; i += 256) {
        int j = c0 + i;
        nb[i] = (j < TOPK) ? tnms[b * TOPK + j]
                           : make_float4(0.0f, 0.0f, 0.0f, 0.0f);
    }
    __syncthreads();

    const int r0 = rb * 64;
    const int r = r0 + (tid & 63);
    const int q = tid >> 6;
    float4 bi = (r < TOPK) ? tnms[b * TOPK + r]
                           : make_float4(0.0f, 0.0f, 0.0f, 0.0f);
    const float area_i = (bi.z - bi.x) * (bi.w - bi.y);

    u64* mrow = mask + ((size_t)b * ROWPAD + r) * NW;
#pragma unroll
    for (int wi = 0; wi < 3; ++wi) {
        const int w = z * 12 + q + wi * 4;       // word 0..23
        u64 bits = 0ULL;
        if (w * 64 + 63 > r0) {                  // uniform triangle test
            const int jbase = (w - z * 12) * 64; // LDS base for this word
            const int j0 = w * 64;
#pragma unroll 4
            for (int l = 0; l < 64; ++l) {
                float4 bj = nb[jbase + l];       // wave-uniform -> broadcast
                float lx = fmaxf(bi.x, bj.x), ly = fmaxf(bi.y, bj.y);
                float rx = fminf(bi.z, bj.z), ry = fminf(bi.w, bj.w);
                float iw = fmaxf(rx - lx, 0.0f), ih = fmaxf(ry - ly, 0.0f);
                float inter = iw * ih;
                if (__ballot(inter > 0.0f)) {    // exact gate: inter==0 => iou==0
                    float area_j = (bj.z - bj.x) * (bj.w - bj.y);
                    float iou = inter / (area_i + area_j - inter + 1e-7f);
                    bits |= ((iou > IOU_TH) && (j0 + l > r)) ? (1ULL << l) : 0ULL;
                }
            }
        }
        mrow[w] = bits;
        if (z == 1 && r0 >= 768)                 // cover unlaunched z=0 words
            mrow[w - 12] = 0ULL;                 // cols 0..767 all sub-diagonal here
    }
}

// ---------------------------------------------------------------------------
// Kernel 4 v4: block-parallel greedy scan with zero-block fast path.
// ---------------------------------------------------------------------------
__device__ __forceinline__ void dense_block(const u64* ss, int t, u64& acc, int ml) {
    const int lane = threadIdx.x;
    u64 rword = ss[lane * NW + t];           // row `lane`'s word t (one parallel read)
    u64 dead = __shfl(acc, t);               // incoming suppression word t (uniform)
    u64 kb = 0ULL;
#pragma unroll
    for (int ii = 0; ii < 64; ++ii) {        // serial greedy closure, ALU-only
        u32 rlo = (u32)__builtin_amdgcn_readlane((int)(u32)(rword & 0xFFFFFFFFu), ii);
        u32 rhi = (u32)__builtin_amdgcn_readlane((int)(u32)(rword >> 32), ii);
        u64 row = ((u64)rhi << 32) | rlo;
        if (!((dead >> ii) & 1ULL)) { dead |= row; kb |= (1ULL << ii); }
    }
    u64 a0 = 0, a1 = 0, a2 = 0, a3 = 0;      // apply: 4 independent chains
#pragma unroll
    for (int q = 0; q < 16; ++q) {
        u64 v0 = ss[(4 * q + 0) * NW + ml];
        u64 v1 = ss[(4 * q + 1) * NW + ml];
        u64 v2 = ss[(4 * q + 2) * NW + ml];
        u64 v3 = ss[(4 * q + 3) * NW + ml];
        a0 |= ((kb >> (4 * q + 0)) & 1ULL) ? v0 : 0ULL;
        a1 |= ((kb >> (4 * q + 1)) & 1ULL) ? v1 : 0ULL;
        a2 |= ((kb >> (4 * q + 2)) & 1ULL) ? v2 : 0ULL;
        a3 |= ((kb >> (4 * q + 3)) & 1ULL) ? v3 : 0ULL;
    }
    acc |= a0 | a1 | a2 | a3;
}

__device__ __forceinline__ void step_block(uint4 (&R)[12], int t, u64& acc, int ml,
                                           const uint4* g4, u64* sbuf) {
    const int lane = threadIdx.x;
    u32 nz = 0;
#pragma unroll
    for (int i = 0; i < 12; ++i) nz |= (R[i].x | R[i].y | R[i].z | R[i].w);
    const u64 anym = __ballot(nz != 0);      // wave-uniform
    if (anym) {                              // rare: stage to LDS for dense path
        uint4* l4 = (uint4*)sbuf;
#pragma unroll
        for (int i = 0; i < 12; ++i) l4[i * 64 + lane] = R[i];
    }
    if (t + 2 < NBLK) {                      // prefetch block t+2 into R
#pragma unroll
        for (int i = 0; i < 12; ++i) R[i] = g4[(size_t)(t + 2) * 768 + i * 64 + lane];
    }
    if (anym) dense_block(sbuf, t, acc, ml);
    // else: all-zero block -> acc unchanged, nothing else to do
}

__global__ __launch_bounds__(64) void k_scan(const u64* __restrict__ mask,
                                             const float4* __restrict__ tbox,
                                             const float* __restrict__ tsc,
                                             const int* __restrict__ tcl,
                                             float* __restrict__ out) {
    __shared__ u64 sbuf[64 * NW];                // 12 KiB, single buffer
    const int b = blockIdx.x;
    const int lane = threadIdx.x;
    float* outb = out + (size_t)b * MAXDET * 6;
    for (int i = lane; i < MAXDET * 6; i += 64) outb[i] = 0.0f;
    __syncthreads();   // drain zero-fill stores before detection writes

    // valid bitset: bit j of word `lane` (lanes 0..23), vectorized float4 reads
    u64 validw = 0ULL;
    if (lane < NW) {
        const float4* t4 = (const float4*)(tsc + (size_t)b * TOPK);
#pragma unroll
        for (int q = 0; q < 16; ++q) {
            int i4 = lane * 16 + q;
            if (i4 < TOPK / 4) {
                float4 v = t4[i4];
                int base = q * 4;
                if (v.x > CONF) validw |= (1ULL << (base + 0));
                if (v.y > CONF) validw |= (1ULL << (base + 1));
                if (v.z > CONF) validw |= (1ULL << (base + 2));
                if (v.w > CONF) validw |= (1ULL << (base + 3));
            }
        }
    }
    u64 acc = (lane < NW) ? ~validw : ~0ULL;     // supp word `lane`; pads pre-suppressed

    const u64* mbase = mask + (size_t)b * ROWPAD * NW;
    const uint4* g4 = (const uint4*)mbase;       // 768 uint4 per 64-row block
    const int ml = (lane < NW) ? lane : 0;       // clamped word index for apply

    uint4 rA[12], rB[12];
#pragma unroll
    for (int i = 0; i < 12; ++i) rA[i] = g4[0 * 768 + i * 64 + lane];   // blk0
#pragma unroll
    for (int i = 0; i < 12; ++i) rB[i] = g4[1 * 768 + i * 64 + lane];   // blk1

    for (int tt = 0; tt < 12; ++tt) {            // rolled outer loop (I-cache)
        step_block(rA, 2 * tt,     acc, ml, g4, sbuf);   // even block (rA)
        step_block(rB, 2 * tt + 1, acc, ml, g4, sbuf);   // odd block (rB)
    }

    // compaction: keep = ~supp (invalid & pad bits already 1 in acc)
    u64 keepw = (lane < NW) ? ~acc : 0ULL;
    int cnt = __popcll(keepw);
    int pre = cnt;
#pragma unroll
    for (int d = 1; d < 64; d <<= 1) {
        int o = __shfl_up(pre, d);
        if (lane >= d) pre += o;
    }
    int rbase = pre - cnt;
    u64 m = keepw;
    int idx = 0;
    while (m) {
        int l = __ffsll((long long)m) - 1;
        m &= m - 1;
        int r = rbase + idx; ++idx;
        if (r < MAXDET) {
            int j = lane * 64 + l;
            float4 bx = tbox[b * TOPK + j];
            float sc = tsc[b * TOPK + j];
            int c = tcl[b * TOPK + j];
            float* o6 = outb + r * 6;
            o6[0] = bx.x; o6[1] = bx.y; o6[2] = bx.z; o6[3] = bx.w;
            o6[4] = sc;   o6[5] = (float)c;
        }
    }
}

// ---------------------------------------------------------------------------
extern "C" void kernel_launch(void* const* d_in, const int* in_sizes, int n_in,
                              void* d_out, int out_size, void* d_ws, size_t ws_size,
                              hipStream_t stream) {
    const float* pred = (const float*)d_in[0];
    float* out = (float*)d_out;
    char* ws = (char*)d_ws;
    if (ws_size < WS_NEED) return;

    u64*    cand = (u64*)   (ws + OFF_CAND);
    float4* tbox = (float4*)(ws + OFF_TBOX);
    float4* tnms = (float4*)(ws + OFF_TNMS);
    float*  tsc  = (float*) (ws + OFF_TSC);
    int*    tcl  = (int*)   (ws + OFF_TCL);
    u64*    mask = (u64*)   (ws + OFF_MASK);

    k_sortchunk<<<dim3(NCH, NIMG), 1024, 0, stream>>>(pred, cand);
    k_merge_gather<<<NIMG, 1024, 0, stream>>>(pred, cand, tbox, tnms, tsc, tcl);
    k_mask<<<dim3(36, NIMG), 256, 0, stream>>>(tnms, mask);
    k_scan<<<NIMG, 64, 0, stream>>>(mask, tbox, tsc, tcl, out);
}

// Round 11
// 221.200 us; speedup vs baseline: 2.2330x; 1.0689x over previous
//
#include <hip/hip_runtime.h>
#include <stdint.h>

typedef unsigned long long u64;
typedef unsigned int u32;

#define NCLS 80
#define NA   8400
#define NIMG 32
#define TOPK 1500
#define MAXDET 300
#define NW 24              // ceil(1500/64) words per suppression row
#define NBLK 24            // 64-row blocks in the scan
#define ROWPAD (NBLK * 64) // 1536 padded mask rows per image
#define CONF 0.25f
#define IOU_TH 0.45f

#define CHUNK 1024         // per-block sort size
#define NCH   9            // 9*1024 = 9216 >= 8400
#define NPAD  (NCH * CHUNK)

// ---- workspace layout (bytes) ----
#define OFF_CAND   ((size_t)0)                             // NIMG*NPAD*8   (2.36MB)
#define OFF_TBOX   (OFF_CAND + (size_t)NIMG*NPAD*8)        // NIMG*TOPK*16
#define OFF_TNMS   (OFF_TBOX + (size_t)NIMG*TOPK*16)       // NIMG*TOPK*16
#define OFF_TSC    (OFF_TNMS + (size_t)NIMG*TOPK*16)       // NIMG*TOPK*4
#define OFF_TCL    (OFF_TSC  + (size_t)NIMG*TOPK*4)        // NIMG*TOPK*4
#define OFF_MASK   (OFF_TCL  + (size_t)NIMG*TOPK*4)        // NIMG*ROWPAD*NW*8
#define OFF_SUMM   (OFF_MASK + (size_t)NIMG*ROWPAD*NW*8)   // NIMG*4
#define WS_NEED    (OFF_SUMM + (size_t)NIMG*4)             // ~13.7 MB

// key = [~ordered(msc):32][anchor:14][cls:7][0:11]; pad anchors (a>=NA) = ~0ULL.
// Real keys are unique (anchor field) and strictly < pad keys, so ascending
// rank order == lax.top_k order (descending score, ascending index).

// ---------------------------------------------------------------------------
// Kernel 1: full-occupancy score/argmax + key build; writes keys into cand
// (unsorted), zeroes the scan summary. Pure coalesced HBM read of 86 MB.
// ---------------------------------------------------------------------------
__global__ __launch_bounds__(256) void k_score(const float* __restrict__ pred,
                                               u64* __restrict__ cand,
                                               u32* __restrict__ summary) {
    const int a = blockIdx.x * 256 + threadIdx.x;   // grid.x = NPAD/256: a < NPAD
    const int b = blockIdx.y;
    if (a == 0) summary[b] = 0;                     // zero before k_mask atomics
    u64 key = ~0ULL;
    if (a < NA) {
        const float* pb = pred + (size_t)b * (4 + NCLS) * NA;
        float best = pb[(size_t)4 * NA + a];
        int bi = 0;
#pragma unroll 8
        for (int cc = 1; cc < NCLS; ++cc) {
            float v = pb[(size_t)(4 + cc) * NA + a];
            if (v > best) { best = v; bi = cc; }    // strict >: first max (jnp.argmax)
        }
        float msc = (best > CONF) ? best : -1.0f;
        u32 u = __float_as_uint(msc);
        u = (u & 0x80000000u) ? ~u : (u | 0x80000000u);
        key = ((u64)(~u) << 32) | ((u64)(u32)a << 18) | ((u64)(u32)bi << 11);
    }
    cand[(size_t)b * NPAD + a] = key;
}

// ---------------------------------------------------------------------------
// Kernel 2: in-place per-chunk bitonic sort (1024 keys, 512 thr, 55 passes).
// ---------------------------------------------------------------------------
__global__ __launch_bounds__(512) void k_sortchunk(u64* __restrict__ cand) {
    __shared__ u64 s[CHUNK];                        // 8 KB
    const int tid = threadIdx.x;
    u64* cb = cand + ((size_t)blockIdx.y * NCH + blockIdx.x) * CHUNK;
    s[tid] = cb[tid];
    s[tid + 512] = cb[tid + 512];
    __syncthreads();

    for (u32 k = 2; k <= CHUNK; k <<= 1) {
        for (u32 j = k >> 1; j > 0; j >>= 1) {
            int t = tid;                            // exactly CHUNK/2 slots
            int i = 2 * t - (t & (j - 1));
            u64 x = s[i], y = s[i + j];
            bool asc = (i & k) == 0;
            if ((x > y) == asc) { s[i] = y; s[i + j] = x; }
            __syncthreads();
        }
    }

    cb[tid] = s[tid];
    cb[tid + 512] = s[tid + 512];
}

// ---------------------------------------------------------------------------
// Kernel 3: rank-based merge + gather (replaces the serial merge kernel).
// Each candidate computes exact global rank = idx + sum of branchless
// lower_bounds in the 8 other sorted chunks (keys unique -> exact).
// rank < 1500 -> decode anchor/class, gather box, write tbox/tnms/tsc/tcl.
// ---------------------------------------------------------------------------
__global__ __launch_bounds__(256) void k_rank_gather(const float* __restrict__ pred,
                                                     const u64* __restrict__ cand,
                                                     float4* __restrict__ tbox,
                                                     float4* __restrict__ tnms,
                                                     float* __restrict__ tsc,
                                                     int* __restrict__ tcl) {
#pragma clang fp contract(off)
    const int gid = blockIdx.x * 256 + threadIdx.x; // < NIMG*NPAD
    const int b = gid / NPAD;
    const int e = gid - b * NPAD;
    const int c = e >> 10;
    const int idx = e & 1023;
    const u64* img = cand + (size_t)b * NPAD;
    const u64 key = img[(c << 10) + idx];
    if (key == ~0ULL) return;                       // pad

    int rank = idx;
    for (int c2 = 0; c2 < NCH; ++c2) {
        if (c2 == c) continue;
        const u64* base = img + (c2 << 10);
        int pos = 0;
#pragma unroll
        for (int st = 512; st > 0; st >>= 1)
            if (base[pos + st - 1] < key) pos += st;
        rank += pos;                                // count of keys < key
    }
    if (rank >= TOPK) return;

    const int a = (int)((key >> 18) & 0x3FFFu);
    const int cl = (int)((key >> 11) & 0x7Fu);
    u32 ou = ~((u32)(key >> 32));
    u32 fb = (ou & 0x80000000u) ? (ou ^ 0x80000000u) : ~ou;
    const float msc = __uint_as_float(fb);

    const float* pb = pred + (size_t)b * (4 + NCLS) * NA;
    const float C1 = (float)((1.0 / 80.0) / 640.0); // mult / IMGSZ
    const float C2 = (float)(1.0 / 80.0);           // mult
    float x1 = pb[a], y1 = pb[NA + a], x2 = pb[2 * NA + a], y2 = pb[3 * NA + a];
    float off = (float)cl * C2;
    tbox[b * TOPK + rank] = make_float4(x1, y1, x2, y2);
    tnms[b * TOPK + rank] = make_float4(x1 * C1 + off, y1 * C1 + off,
                                        x2 * C1 + off, y2 * C1 + off);
    tsc[b * TOPK + rank] = msc;
    tcl[b * TOPK + rank] = cl;
}

// ---------------------------------------------------------------------------
// Kernel 4: suppression bit matrix, column-split + ballot-gated divide,
// + per-row-block nonzero summary (24-bit map per image) for the scan.
// ---------------------------------------------------------------------------
__global__ __launch_bounds__(256) void k_mask(const float4* __restrict__ tnms,
                                              u64* __restrict__ mask,
                                              u32* __restrict__ summary) {
#pragma clang fp contract(off)
    __shared__ float4 nb[768];                   // 12 KB column slice
    const int b = blockIdx.y;
    const int idx = blockIdx.x;
    const int z = (idx < 24) ? 1 : 0;
    const int rb = (idx < 24) ? idx : (idx - 24);
    const int c0 = z * 768;
    const int tid = threadIdx.x;

    for (int i = tid; i < 768; i += 256) {
        int j = c0 + i;
        nb[i] = (j < TOPK) ? tnms[b * TOPK + j]
                           : make_float4(0.0f, 0.0f, 0.0f, 0.0f);
    }
    __syncthreads();

    const int r0 = rb * 64;
    const int r = r0 + (tid & 63);
    const int q = tid >> 6;
    float4 bi = (r < TOPK) ? tnms[b * TOPK + r]
                           : make_float4(0.0f, 0.0f, 0.0f, 0.0f);
    const float area_i = (bi.z - bi.x) * (bi.w - bi.y);

    u64* mrow = mask + ((size_t)b * ROWPAD + r) * NW;
    u32 haveany = 0;
#pragma unroll
    for (int wi = 0; wi < 3; ++wi) {
        const int w = z * 12 + q + wi * 4;       // word 0..23
        u64 bits = 0ULL;
        if (w * 64 + 63 > r0) {                  // uniform triangle test
            const int jbase = (w - z * 12) * 64; // LDS base for this word
            const int j0 = w * 64;
#pragma unroll 4
            for (int l = 0; l < 64; ++l) {
                float4 bj = nb[jbase + l];       // wave-uniform -> broadcast
                float lx = fmaxf(bi.x, bj.x), ly = fmaxf(bi.y, bj.y);
                float rx = fminf(bi.z, bj.z), ry = fminf(bi.w, bj.w);
                float iw = fmaxf(rx - lx, 0.0f), ih = fmaxf(ry - ly, 0.0f);
                float inter = iw * ih;
                if (__ballot(inter > 0.0f)) {    // exact gate: inter==0 => iou==0
                    float area_j = (bj.z - bj.x) * (bj.w - bj.y);
                    float iou = inter / (area_i + area_j - inter + 1e-7f);
                    bits |= ((iou > IOU_TH) && (j0 + l > r)) ? (1ULL << l) : 0ULL;
                }
            }
        }
        mrow[w] = bits;
        haveany |= (bits != 0ULL) ? 1u : 0u;
        if (z == 1 && r0 >= 768)                 // cover unlaunched z=0 words
            mrow[w - 12] = 0ULL;                 // cols 0..767 all sub-diagonal here
    }
    if (haveany) atomicOr(&summary[b], 1u << rb);
}

// ---------------------------------------------------------------------------
// Kernel 5: greedy scan; loads ONLY row-blocks flagged nonzero in summary.
// ---------------------------------------------------------------------------
__device__ __forceinline__ void dense_block(const u64* ss, int t, u64& acc, int ml) {
    const int lane = threadIdx.x;
    u64 rword = ss[lane * NW + t];           // row `lane`'s word t
    u64 dead = __shfl(acc, t);               // incoming suppression word t (uniform)
    u64 kb = 0ULL;
#pragma unroll
    for (int ii = 0; ii < 64; ++ii) {        // serial greedy closure, ALU-only
        u32 rlo = (u32)__builtin_amdgcn_readlane((int)(u32)(rword & 0xFFFFFFFFu), ii);
        u32 rhi = (u32)__builtin_amdgcn_readlane((int)(u32)(rword >> 32), ii);
        u64 row = ((u64)rhi << 32) | rlo;
        if (!((dead >> ii) & 1ULL)) { dead |= row; kb |= (1ULL << ii); }
    }
    u64 a0 = 0, a1 = 0, a2 = 0, a3 = 0;      // apply: 4 independent chains
#pragma unroll
    for (int q = 0; q < 16; ++q) {
        u64 v0 = ss[(4 * q + 0) * NW + ml];
        u64 v1 = ss[(4 * q + 1) * NW + ml];
        u64 v2 = ss[(4 * q + 2) * NW + ml];
        u64 v3 = ss[(4 * q + 3) * NW + ml];
        a0 |= ((kb >> (4 * q + 0)) & 1ULL) ? v0 : 0ULL;
        a1 |= ((kb >> (4 * q + 1)) & 1ULL) ? v1 : 0ULL;
        a2 |= ((kb >> (4 * q + 2)) & 1ULL) ? v2 : 0ULL;
        a3 |= ((kb >> (4 * q + 3)) & 1ULL) ? v3 : 0ULL;
    }
    acc |= a0 | a1 | a2 | a3;
}

__global__ __launch_bounds__(64) void k_scan(const u64* __restrict__ mask,
                                             const float4* __restrict__ tbox,
                                             const float* __restrict__ tsc,
                                             const int* __restrict__ tcl,
                                             const u32* __restrict__ summary,
                                             float* __restrict__ out) {
    __shared__ u64 sbuf[64 * NW];                // 12 KiB
    const int b = blockIdx.x;
    const int lane = threadIdx.x;
    float* outb = out + (size_t)b * MAXDET * 6;
    for (int i = lane; i < MAXDET * 6; i += 64) outb[i] = 0.0f;
    __syncthreads();   // drain zero-fill stores before detection writes

    // valid bitset: bit j of word `lane` (lanes 0..23), vectorized float4 reads
    u64 validw = 0ULL;
    if (lane < NW) {
        const float4* t4 = (const float4*)(tsc + (size_t)b * TOPK);
#pragma unroll
        for (int q = 0; q < 16; ++q) {
            int i4 = lane * 16 + q;
            if (i4 < TOPK / 4) {
                float4 v = t4[i4];
                int base = q * 4;
                if (v.x > CONF) validw |= (1ULL << (base + 0));
                if (v.y > CONF) validw |= (1ULL << (base + 1));
                if (v.z > CONF) validw |= (1ULL << (base + 2));
                if (v.w > CONF) validw |= (1ULL << (base + 3));
            }
        }
    }
    u64 acc = (lane < NW) ? ~validw : ~0ULL;     // supp word `lane`; pads pre-suppressed

    const u64* mbase = mask + (size_t)b * ROWPAD * NW;
    const uint4* g4 = (const uint4*)mbase;       // 768 uint4 per 64-row block
    const int ml = (lane < NW) ? lane : 0;       // clamped word index for apply
    const u32 summ = summary[b];

    for (int t = 0; t < NBLK; ++t) {
        if (!((summ >> t) & 1u)) continue;       // all-zero block: provably a no-op
        uint4 R[12];
#pragma unroll
        for (int i = 0; i < 12; ++i) R[i] = g4[(size_t)t * 768 + i * 64 + lane];
        uint4* l4 = (uint4*)sbuf;
#pragma unroll
        for (int i = 0; i < 12; ++i) l4[i * 64 + lane] = R[i];
        dense_block(sbuf, t, acc, ml);
    }

    // compaction: keep = ~supp (invalid & pad bits already 1 in acc)
    u64 keepw = (lane < NW) ? ~acc : 0ULL;
    int cnt = __popcll(keepw);
    int pre = cnt;
#pragma unroll
    for (int d = 1; d < 64; d <<= 1) {
        int o = __shfl_up(pre, d);
        if (lane >= d) pre += o;
    }
    int rbase = pre - cnt;
    u64 m = keepw;
    int idx = 0;
    while (m) {
        int l = __ffsll((long long)m) - 1;
        m &= m - 1;
        int r = rbase + idx; ++idx;
        if (r < MAXDET) {
            int j = lane * 64 + l;
            float4 bx = tbox[b * TOPK + j];
            float sc = tsc[b * TOPK + j];
            int c = tcl[b * TOPK + j];
            float* o6 = outb + r * 6;
            o6[0] = bx.x; o6[1] = bx.y; o6[2] = bx.z; o6[3] = bx.w;
            o6[4] = sc;   o6[5] = (float)c;
        }
    }
}

// ---------------------------------------------------------------------------
extern "C" void kernel_launch(void* const* d_in, const int* in_sizes, int n_in,
                              void* d_out, int out_size, void* d_ws, size_t ws_size,
                              hipStream_t stream) {
    const float* pred = (const float*)d_in[0];
    float* out = (float*)d_out;
    char* ws = (char*)d_ws;
    if (ws_size < WS_NEED) return;

    u64*    cand = (u64*)   (ws + OFF_CAND);
    float4* tbox = (float4*)(ws + OFF_TBOX);
    float4* tnms = (float4*)(ws + OFF_TNMS);
    float*  tsc  = (float*) (ws + OFF_TSC);
    int*    tcl  = (int*)   (ws + OFF_TCL);
    u64*    mask = (u64*)   (ws + OFF_MASK);
    u32*    summ = (u32*)   (ws + OFF_SUMM);

    k_score<<<dim3(NPAD / 256, NIMG), 256, 0, stream>>>(pred, cand, summ);
    k_sortchunk<<<dim3(NCH, NIMG), 512, 0, stream>>>(cand);
    k_rank_gather<<<(NIMG * NPAD) / 256, 256, 0, stream>>>(pred, cand, tbox, tnms, tsc, tcl);
    k_mask<<<dim3(36, NIMG), 256, 0, stream>>>(tnms, mask, summ);
    k_scan<<<NIMG, 64, 0, stream>>>(mask, tbox, tsc, tcl, summ, out);
}